// Round 11
// baseline (473.352 us; speedup 1.0000x reference)
//
#include <hip/hip_runtime.h>
#include <stdint.h>

typedef _Float16 half8 __attribute__((ext_vector_type(8)));
typedef float float4v __attribute__((ext_vector_type(4)));

#define H_IN 256
#define W_IN 256
#define H_OUT 254
#define W_OUT 254
#define T_COLS 68
#define A_ROWS 408                    // 6 in-rows * 68 cols
#define A_BYTES (A_ROWS * 128)        // 52224
#define B_SLAB  16384                 // one tap: 128co x 64cin fp16
#define SMEM_BYTES (2*A_BYTES + 2*B_SLAB + 2048)   // 139264

// ---------------------------------------------------------------------------
// Pack conv_weight (OIHW fp32) into DMA-ready tap slabs:
//   Bp[tap][co][s][e] : s = (h*4+q) ^ (co&7), cin = h*32+q*8+e  (16B granules)
// Read side: lane(q,lr), frag(n,h): slot (h*4+q)^(co&7) -> <=2-way banks
// (key co&7: lr..lr+7 all distinct; lr vs lr+8 same slot, addr+1024 = same
//  bank 2-way = free. v8's (co>>2)&3 key left lr-quads 4-way.)
// ---------------------------------------------------------------------------
__global__ void pack_w_kernel(const float* __restrict__ w, _Float16* __restrict__ Bp) {
    int idx = blockIdx.x * 256 + threadIdx.x;   // 9*128*8*8 = 73728
    if (idx >= 73728) return;
    int tap = idx >> 13;
    int rem = idx & 8191;
    int co  = rem >> 6;
    int s   = (rem >> 3) & 7;
    int e   = rem & 7;
    int hq  = s ^ (co & 7);
    int h   = hq >> 2, q = hq & 3;
    int cin = h * 32 + q * 8 + e;
    int kh  = tap / 3, kw = tap - kh * 3;
    Bp[idx] = (_Float16)w[(co * 64 + cin) * 9 + kh * 3 + kw];
}

// A-tile swizzle key (bank-floor for 16-consecutive-row reads + stride-4 writes)
__device__ __forceinline__ int akey(int row) {
    return (((row & 7) ^ ((row >> 3) & 7)) << 4);
}

// ---------------------------------------------------------------------------
// v11: persistent blocks, A double-buffered, tap-level B ring-2.
// grid (4,4,16) = 256 blocks = 1/CU. 512 thr = 8 waves x 64px x 64co.
// Each block walks 16 tiles of 4 output rows. Per tile: 9 taps, each
// {waitcnt; s_barrier; issue next-tap DMA; 16 ds_reads; 32 MFMA}.
// A-loads for tile t+1 issue at tap 7 (held in regs), ds_write at tile end
// into buf^1 -> staging HBM overlaps the next tile's compute window.
// MFMA floor: 73us. Per-tap CU arithmetic: MFMA 1.24k cyc vs LDS ~500 cyc.
// ---------------------------------------------------------------------------
__global__ __launch_bounds__(512, 2)
void conv_v11_kernel(const float* __restrict__ x,
                     const _Float16* __restrict__ Bp,
                     const float* __restrict__ bias,
                     float* __restrict__ out) {
    extern __shared__ __align__(16) char smem[];
    char*  AldsBase = smem;                         // [2][A_BYTES]
    char*  Blds     = smem + 2 * A_BYTES;           // [2][B_SLAB]
    float* minbuf   = (float*)(smem + 2 * A_BYTES + 2 * B_SLAB); // [2][256]

    const int tid  = threadIdx.x;
    const int lane = tid & 63;
    const int wave = tid >> 6;      // 0..7
    const int ow0  = blockIdx.x * 64;
    const int strip0 = blockIdx.y * 64;
    const int nb   = blockIdx.z;
    const int wr   = wave >> 1;     // output row within tile (0..3)
    const int wc   = wave & 1;      // co half
    const int q    = lane >> 4;
    const int lr   = lane & 15;

    const float* xb = x + (size_t)nb * (64 * H_IN * W_IN);

    // ---- staging descriptors: 816 items (8cin-oct x 4px col-quad)
    int id0 = tid;
    int id1 = (tid < 304) ? (512 + tid) : tid;   // dup item0-range if invalid (uniform vmcnt)
    const bool w1 = (tid < 304);
    int  s_oct[2], s_row0[2], s_r[2], s_iw[2];
    {
        int ids[2] = {id0, id1};
#pragma unroll
        for (int k = 0; k < 2; ++k) {
            int o   = (unsigned)ids[k] / 102u;
            int pxq = ids[k] - o * 102;
            int r   = (unsigned)pxq / 17u;
            int c4  = (pxq - r * 17) * 4;
            s_oct[k] = o; s_row0[k] = pxq * 4; s_r[k] = r;
            int iw = ow0 + c4; if (iw > W_IN - 4) iw = W_IN - 4;
            s_iw[k] = iw;
        }
    }
    float4v f[2][8];   // held staging registers (64 VGPR, live taps7..end)

    auto issue_loads = [&](int ih0) {
#pragma unroll
        for (int k = 0; k < 2; ++k) {
            int ih = ih0 + s_r[k]; if (ih > H_IN - 1) ih = H_IN - 1;
            const float* src = xb + (size_t)(s_oct[k] * 8) * (H_IN * W_IN)
                                  + (size_t)ih * W_IN + s_iw[k];
#pragma unroll
            for (int u = 0; u < 8; ++u)
                f[k][u] = *(const float4v*)(src + (size_t)u * (H_IN * W_IN));
        }
    };
    auto write_A = [&](char* abuf) {
#pragma unroll
        for (int k = 0; k < 2; ++k) {
            if (k == 1 && !w1) continue;
#pragma unroll
            for (int j = 0; j < 4; ++j) {
                int row = s_row0[k] + j;
                half8 hv;
#pragma unroll
                for (int u = 0; u < 8; ++u) hv[u] = (_Float16)f[k][u][j];
                *(half8*)(abuf + row * 128 + ((s_oct[k] * 16) ^ akey(row))) = hv;
            }
        }
    };
    auto dma_slab = [&](int srctap, int slot) {
#pragma unroll
        for (int i = 0; i < 2; ++i) {
            const char* src = (const char*)Bp + (size_t)srctap * B_SLAB + i * 8192 + tid * 16;
            char* dst = Blds + slot * B_SLAB + i * 8192 + (tid & ~63) * 16;
            __builtin_amdgcn_global_load_lds(
                (const __attribute__((address_space(1))) uint32_t*)src,
                (__attribute__((address_space(3))) uint32_t*)dst, 16, 0, 0);
        }
    };

    float bv[4];
#pragma unroll
    for (int n = 0; n < 4; ++n) bv[n] = bias[wc * 64 + n * 16 + lr];

    // ---- prologue: B slab(t0,tap0) + A tile0
    dma_slab(0, 0);
    __builtin_amdgcn_sched_barrier(0);
    issue_loads(strip0);
    // compiler emits vmcnt wait for f-use below (drains DMA too: in-order)
    write_A(AldsBase);

    const int bco = (wc * 64 + lr) * 128;
    const int bkey = ((wc * 64 + lr) & 7);

    for (int t = 0; t < 16; ++t) {
        char* abuf = AldsBase + (t & 1) * A_BYTES;
        const int oh0 = strip0 + t * 4;

        float4v acc[4][4];
#pragma unroll
        for (int m = 0; m < 4; ++m)
#pragma unroll
            for (int n = 0; n < 4; ++n)
#pragma unroll
                for (int i = 0; i < 4; ++i) acc[m][n][i] = 0.0f;

#pragma unroll
        for (int g = 0; g < 9; ++g) {
            // ---- wait for slab (t,g) [issued one tap ago], then barrier.
            // tap8: 16 A-loads issued at tap7 sit AHEAD of DMA(g=8)?? no:
            // DMA(g=8) was issued at tap7 start, BEFORE the A-loads
            // (sched_barrier-pinned) -> vmcnt(16) retires exactly that DMA.
            if (g == 8) asm volatile("s_waitcnt vmcnt(16) lgkmcnt(0)" ::: "memory");
            else        asm volatile("s_waitcnt vmcnt(0) lgkmcnt(0)" ::: "memory");
            __builtin_amdgcn_s_barrier();

            // ---- issue DMA for next slab: src tap (g+1)%9, slot (t+g+1)&1
            dma_slab((g + 1 == 9) ? 0 : (g + 1), (t + g + 1) & 1);
            __builtin_amdgcn_sched_barrier(0);
            if (g == 7) {
                issue_loads(oh0 + 4);   // tile t+1 (t=15: clamped rows, unused)
                __builtin_amdgcn_sched_barrier(0);
            }

            const int kh = g / 3, kw = g - kh * 3;
            const char* slab = Blds + ((t + g) & 1) * B_SLAB;

            __builtin_amdgcn_s_setprio(1);
#pragma unroll
            for (int h = 0; h < 2; ++h) {
                const int kb = h * 64 + q * 16;
                half8 a[4], b[4];
#pragma unroll
                for (int n = 0; n < 4; ++n)
                    b[n] = *(const half8*)(slab + bco + n * 2048
                                           + (((h * 4 + q) ^ bkey) << 4));
#pragma unroll
                for (int m = 0; m < 4; ++m) {
                    int row = (wr + kh) * T_COLS + m * 16 + lr + kw;
                    a[m] = *(const half8*)(abuf + row * 128 + (kb ^ akey(row)));
                }
#pragma unroll
                for (int m = 0; m < 4; ++m)
#pragma unroll
                    for (int n = 0; n < 4; ++n)
                        acc[m][n] = __builtin_amdgcn_mfma_f32_16x16x32_f16(
                            a[m], b[n], acc[m][n], 0, 0, 0);
            }
            __builtin_amdgcn_s_setprio(0);
        }

        // ---- epilogue: + bias, min over co, publish per-px min
#pragma unroll
        for (int m = 0; m < 4; ++m) {
            float4v v;
#pragma unroll
            for (int n = 0; n < 4; ++n) {
#pragma unroll
                for (int i = 0; i < 4; ++i) {
                    float tt = acc[m][n][i] + bv[n];
                    v[i] = (n == 0) ? tt : fminf(v[i], tt);
                }
            }
#pragma unroll
            for (int off = 1; off < 16; off <<= 1)
#pragma unroll
                for (int i = 0; i < 4; ++i)
                    v[i] = fminf(v[i], __shfl_xor(v[i], off, 64));
            if (lr == 0) {
#pragma unroll
                for (int i = 0; i < 4; ++i)
                    minbuf[wc * 256 + wr * 64 + m * 16 + q * 4 + i] = v[i];
            }
        }
        asm volatile("s_waitcnt lgkmcnt(0)" ::: "memory");
        __builtin_amdgcn_s_barrier();

        if (tid < 256) {
            int r = tid >> 6, c = tid & 63;
            int oh = oh0 + r, ow = ow0 + c;
            if (oh < H_OUT && ow < W_OUT) {
                float mv = fminf(minbuf[tid], minbuf[256 + tid]);
                out[((size_t)nb * H_OUT + oh) * W_OUT + ow] = tanhf(tanhf(mv));
            }
        }

        // ---- land tile t+1 into the other A buffer (reads gated by next
        // tap0's barrier; compiler inserts the precise vmcnt for f-use)
        write_A(AldsBase + ((t + 1) & 1) * A_BYTES);
    }
}

extern "C" void kernel_launch(void* const* d_in, const int* in_sizes, int n_in,
                              void* d_out, int out_size, void* d_ws, size_t ws_size,
                              hipStream_t stream) {
    const float* x    = (const float*)d_in[0];
    const float* w    = (const float*)d_in[1];
    const float* bias = (const float*)d_in[2];
    float* out        = (float*)d_out;
    _Float16* Bp      = (_Float16*)d_ws;   // 147456 B

    static bool attr_set = false;   // idempotent host-side attribute (not device state)
    if (!attr_set) {
        hipFuncSetAttribute((const void*)conv_v11_kernel,
                            hipFuncAttributeMaxDynamicSharedMemorySize, SMEM_BYTES);
        attr_set = true;
    }

    pack_w_kernel<<<dim3(288), dim3(256), 0, stream>>>(w, Bp);
    conv_v11_kernel<<<dim3(4, 4, 16), dim3(512), SMEM_BYTES, stream>>>(x, Bp, bias, out);
}

// Round 12
// 189.255 us; speedup vs baseline: 2.5011x; 2.5011x over previous
//
#include <hip/hip_runtime.h>
#include <stdint.h>

typedef _Float16 half8 __attribute__((ext_vector_type(8)));
typedef float float4v __attribute__((ext_vector_type(4)));
typedef unsigned int uint4v __attribute__((ext_vector_type(4)));

#define H_IN 256
#define W_IN 256
#define H_OUT 254
#define W_OUT 254
#define T_COLS 68
#define A_ROWS 408                    // 6 in-rows * 68 cols
#define A_BYTES (A_ROWS * 128)        // 52224
#define B_SLAB  8192                  // one (tap,h) group: 128co x 32cin fp16
#define B_BYTES (2 * B_SLAB)          // ring-2
#define MIN_BYTES (2 * 256 * 4)
#define SMEM_BYTES (A_BYTES + B_BYTES + MIN_BYTES)   // 70656 -> 2 blocks/CU

// ---------------------------------------------------------------------------
// Pack conv_weight (OIHW fp32) into slab layout (same as v8):
//   Bp3[g][co][s16][e], g=(kh*3+kw)*2+h, s16 = q ^ ((co>>2)&3), cin=h*32+q*8+e
// Read slot q ^ ((lr>>2)&3): 2-way max under the 8-lane phase model.
// ---------------------------------------------------------------------------
__global__ void pack_w_kernel(const float* __restrict__ w, _Float16* __restrict__ Bp3) {
    int idx = blockIdx.x * 256 + threadIdx.x;   // 18*4096 = 73728
    if (idx >= 73728) return;
    int g   = idx >> 12;
    int rem = idx & 4095;
    int co  = rem >> 5;
    int s16 = (rem >> 3) & 3;
    int e   = rem & 7;
    int q   = s16 ^ ((co >> 2) & 3);
    int tap = g >> 1, h = g & 1;
    int cin = h * 32 + q * 8 + e;
    int kh  = tap / 3, kw = tap - kh * 3;
    Bp3[idx] = (_Float16)w[(co * 64 + cin) * 9 + kh * 3 + kw];
}

// A-tile swizzle key
__device__ __forceinline__ int akey(int row) {
    return (((row & 7) ^ ((row >> 3) & 7)) << 4);
}

// ---------------------------------------------------------------------------
// v12: 256 thr, 4 waves x 128px x 64co (v5 geometry: acc=128, spill-free).
//  - Per-wave MFMA cluster 32 (620 cyc/SIMD): other wave's 12 frag reads hide
//    under it -> breaks v8's read/MFMA alternation (wall/group 3100 -> ~1500).
//  - B reg-staged ring-2 (T14): loads pinned at group start, ds_write at end;
//    NO global_load_lds in loop -> kills the 18.4M DMA/ds_read conflict tax.
//  - A-staging item remap (oct fast within wave) -> conflict-free writes.
// 18 groups, 1 lgkm-barrier each. grid (4, 64, 16), LDS 70656 (2 blocks/CU).
// ---------------------------------------------------------------------------
__global__ __launch_bounds__(256, 2)
void conv_v12_kernel(const float* __restrict__ x,
                     const _Float16* __restrict__ Bp3,
                     const float* __restrict__ bias,
                     float* __restrict__ out) {
    extern __shared__ __align__(16) char smem[];
    char*  Alds   = smem;                               // [408 rows][128 B]
    char*  Blds   = smem + A_BYTES;                     // [2][8192 B]
    float* minbuf = (float*)(smem + A_BYTES + B_BYTES); // [2][256]

    const int tid  = threadIdx.x;
    const int lane = tid & 63;
    const int wave = tid >> 6;      // 0..3
    const int ow0  = blockIdx.x * 64;
    const int oh0  = blockIdx.y * 4;
    const int nb   = blockIdx.z;
    const int wr   = wave >> 1;     // px half: 0 -> px 0..127, 1 -> 128..255
    const int wc   = wave & 1;      // co half
    const int q    = lane >> 4;
    const int lr   = lane & 15;

    const uint4v* bsrc = (const uint4v*)Bp3;   // 16B granules, slab = 512

    // ---- prologue: B slab0 -> regs (coalesced, L2)
    uint4v breg0 = bsrc[tid];
    uint4v breg1 = bsrc[tid + 256];

    // ---- stage A tile: 816 items, id = pxq*8 + oct (oct fast within wave:
    // 8 lanes write 8 octets of the same rows -> all 32 banks, conflict-free)
    {
        const float* xb = x + (size_t)nb * (64 * H_IN * W_IN);
#pragma unroll
        for (int k = 0; k < 4; ++k) {
            int id = tid + 256 * k;
            if (id < 816) {
                int pxq = id >> 3;
                int oct = id & 7;
                int r   = (unsigned)pxq / 17u;
                int q4  = pxq - r * 17;
                int row0 = r * T_COLS + q4 * 4;
                int ih   = oh0 + r; if (ih > H_IN - 1) ih = H_IN - 1;
                int iw   = ow0 + q4 * 4; if (iw > W_IN - 4) iw = W_IN - 4;
                const float* src = xb + (size_t)(oct * 8) * (H_IN * W_IN)
                                      + (size_t)ih * W_IN + iw;
                float4v f[8];
#pragma unroll
                for (int u = 0; u < 8; ++u)
                    f[u] = *(const float4v*)(src + (size_t)u * (H_IN * W_IN));
#pragma unroll
                for (int j = 0; j < 4; ++j) {
                    int row = row0 + j;
                    half8 hv;
#pragma unroll
                    for (int u = 0; u < 8; ++u) hv[u] = (_Float16)f[u][j];
                    *(half8*)(Alds + row * 128 + ((oct * 16) ^ akey(row))) = hv;
                }
            }
        }
    }
    // land B slab0 into slot 0
    *(uint4v*)(Blds + tid * 16)         = breg0;
    *(uint4v*)(Blds + (tid + 256) * 16) = breg1;
    __syncthreads();

    float bv[4];
#pragma unroll
    for (int n = 0; n < 4; ++n) bv[n] = bias[wc * 64 + n * 16 + lr];

    const int bslot = (q ^ ((lr >> 2) & 3)) << 4;
    const int bco   = (wc * 64 + lr) * 64;

    float4v acc[8][4];
#pragma unroll
    for (int m = 0; m < 8; ++m)
#pragma unroll
        for (int n = 0; n < 4; ++n)
#pragma unroll
            for (int i = 0; i < 4; ++i) acc[m][n][i] = 0.0f;

#pragma unroll
    for (int g = 0; g < 18; ++g) {
        // ---- T14 issue-early: slab g+1 global->regs, pinned above compute
        if (g < 17) {
            breg0 = bsrc[(g + 1) * 512 + tid];
            breg1 = bsrc[(g + 1) * 512 + tid + 256];
            __builtin_amdgcn_sched_barrier(0);
        }

        const int tap = g >> 1, h = g & 1;
        const int kh = tap / 3, kw = tap - kh * 3;
        const int kb = h * 64 + q * 16;
        const char* slab = Blds + (g & 1) * B_SLAB;

        half8 a[8], b[4];
#pragma unroll
        for (int n = 0; n < 4; ++n)
            b[n] = *(const half8*)(slab + bco + n * 1024 + bslot);
#pragma unroll
        for (int m = 0; m < 8; ++m) {
            int row = (wr * 2 + (m >> 2) + kh) * T_COLS + (m & 3) * 16 + lr + kw;
            a[m] = *(const half8*)(Alds + row * 128 + (kb ^ akey(row)));
        }

        __builtin_amdgcn_s_setprio(1);
#pragma unroll
        for (int m = 0; m < 8; ++m)
#pragma unroll
            for (int n = 0; n < 4; ++n)
                acc[m][n] = __builtin_amdgcn_mfma_f32_16x16x32_f16(
                    a[m], b[n], acc[m][n], 0, 0, 0);
        __builtin_amdgcn_s_setprio(0);

        // ---- write-late: land slab g+1 into slot (g+1)&1 (its readers
        // finished in group g-1, a barrier ago)
        if (g < 17) {
            char* dst = Blds + ((g + 1) & 1) * B_SLAB;
            *(uint4v*)(dst + tid * 16)         = breg0;
            *(uint4v*)(dst + (tid + 256) * 16) = breg1;
        }
        asm volatile("s_waitcnt lgkmcnt(0)" ::: "memory");   // publish write
        __builtin_amdgcn_s_barrier();
    }

    // ---- epilogue: + bias, min over co, double tanh
#pragma unroll
    for (int m = 0; m < 8; ++m) {
        float4v v;
#pragma unroll
        for (int n = 0; n < 4; ++n) {
#pragma unroll
            for (int i = 0; i < 4; ++i) {
                float t = acc[m][n][i] + bv[n];
                v[i] = (n == 0) ? t : fminf(v[i], t);
            }
        }
#pragma unroll
        for (int off = 1; off < 16; off <<= 1)
#pragma unroll
            for (int i = 0; i < 4; ++i)
                v[i] = fminf(v[i], __shfl_xor(v[i], off, 64));
        if (lr == 0) {
#pragma unroll
            for (int i = 0; i < 4; ++i)
                minbuf[wc * 256 + wr * 128 + m * 16 + q * 4 + i] = v[i];
        }
    }
    __syncthreads();

    {
        int r = tid >> 6, c = tid & 63;
        int oh = oh0 + r, ow = ow0 + c;
        if (oh < H_OUT && ow < W_OUT) {
            float mv = fminf(minbuf[tid], minbuf[256 + tid]);
            out[((size_t)nb * H_OUT + oh) * W_OUT + ow] = tanhf(tanhf(mv));
        }
    }
}

extern "C" void kernel_launch(void* const* d_in, const int* in_sizes, int n_in,
                              void* d_out, int out_size, void* d_ws, size_t ws_size,
                              hipStream_t stream) {
    const float* x    = (const float*)d_in[0];
    const float* w    = (const float*)d_in[1];
    const float* bias = (const float*)d_in[2];
    float* out        = (float*)d_out;
    _Float16* Bp3     = (_Float16*)d_ws;   // 147456 B

    pack_w_kernel<<<dim3(288), dim3(256), 0, stream>>>(w, Bp3);
    conv_v12_kernel<<<dim3(4, 64, 16), dim3(256), SMEM_BYTES, stream>>>(x, Bp3, bias, out);
}